// Round 1
// baseline (76.974 us; speedup 1.0000x reference)
//
#include <hip/hip_runtime.h>

// B=2, N=512, C_IN=16, C_OUT=16, HID=64
#define NQ  512
#define CI  16
#define CO  16
#define HIDN 64

// out[z,a,b,i] = sum_h gelu(MLP1(rel,norm))[h] * M[z,b,i,h] + c[z,b,i]
//   M[z,b,i,h] = sum_j W2[(i*16+j)*64 + h] * f[z,b,j]
//   c[z,b,i]   = sum_j b2[i*16+j] * f[z,b,j]
__global__ __launch_bounds__(256) void fused_pairconv_kernel(
    const float* __restrict__ features,   // [2,512,16]
    const float* __restrict__ geometry,   // [2,512,3]
    const float* __restrict__ W1,         // [64,4]
    const float* __restrict__ b1,         // [64]
    const float* __restrict__ W2,         // [256,64]
    const float* __restrict__ b2,         // [256]
    float* __restrict__ out)              // [2,512,512,16]
{
    __shared__ float M_sm[CO * HIDN];   // 1024 floats = 4 KB
    __shared__ float c_sm[CO];
    __shared__ float f_sm[CI];
    __shared__ float W1_sm[HIDN * 4];   // 256
    __shared__ float b1_sm[HIDN];

    const int bid = blockIdx.x;
    const int zb  = bid >> 1;            // 0..1023  (z*512 + b)
    const int a0  = (bid & 1) << 8;      // 0 or 256
    const int z   = zb >> 9;
    const int b   = zb & 511;
    const int tid = threadIdx.x;

    // ---- stage 0: stage small params into LDS ----
    W1_sm[tid] = W1[tid];                          // 256 elems, all threads
    if (tid < HIDN) b1_sm[tid] = b1[tid];
    if (tid < CI)   f_sm[tid]  = features[zb * CI + tid];
    __syncthreads();

    // ---- stage 1: per-(z,b) fused matrix M = W2 contracted with f, plus c ----
    #pragma unroll
    for (int e = 0; e < 4; ++e) {
        int idx = tid + e * 256;        // 0..1023
        int i = idx >> 6;               // C_OUT index
        int hh = idx & 63;              // HID index
        float acc = 0.f;
        #pragma unroll
        for (int j = 0; j < CI; ++j)
            acc = fmaf(f_sm[j], W2[(i * CI + j) * HIDN + hh], acc);
        M_sm[idx] = acc;
    }
    if (tid < CO) {
        float acc = 0.f;
        #pragma unroll
        for (int j = 0; j < CI; ++j)
            acc = fmaf(f_sm[j], b2[tid * CI + j], acc);
        c_sm[tid] = acc;
    }
    __syncthreads();

    // ---- stage 2: one thread per 'a' ----
    const int a = a0 + tid;
    const float* ga = geometry + (size_t)(z * NQ + a) * 3;
    const float* gb = geometry + (size_t)(z * NQ + b) * 3;
    const float rx = gb[0] - ga[0];
    const float ry = gb[1] - ga[1];
    const float rz = gb[2] - ga[2];
    const float nrm = sqrtf(fmaf(rx, rx, fmaf(ry, ry, rz * rz)) + 1e-12f);

    // MLP1 + gelu (JAX default: tanh approximation)
    float hv[HIDN];
    #pragma unroll
    for (int k = 0; k < HIDN; ++k) {
        float pre = b1_sm[k];
        pre = fmaf(rx,  W1_sm[k * 4 + 0], pre);
        pre = fmaf(ry,  W1_sm[k * 4 + 1], pre);
        pre = fmaf(rz,  W1_sm[k * 4 + 2], pre);
        pre = fmaf(nrm, W1_sm[k * 4 + 3], pre);
        float x = pre;
        float u = 0.7978845608028654f * fmaf(0.044715f * x, x * x, x);
        u = fminf(fmaxf(u, -9.f), 9.f);
        float e2 = __builtin_amdgcn_exp2f(2.885390081777927f * u);  // exp(2u)
        float t  = (e2 - 1.f) * __builtin_amdgcn_rcpf(e2 + 1.f);    // tanh(u)
        hv[k] = 0.5f * x * (1.f + t);
    }

    // contraction with M (LDS broadcast reads, float4)
    float o[CO];
    #pragma unroll
    for (int i = 0; i < CO; ++i) o[i] = c_sm[i];
    #pragma unroll
    for (int i = 0; i < CO; ++i) {
        #pragma unroll
        for (int k = 0; k < HIDN; k += 4) {
            const float4 m4 = *reinterpret_cast<const float4*>(&M_sm[i * HIDN + k]);
            o[i] = fmaf(hv[k + 0], m4.x, o[i]);
            o[i] = fmaf(hv[k + 1], m4.y, o[i]);
            o[i] = fmaf(hv[k + 2], m4.z, o[i]);
            o[i] = fmaf(hv[k + 3], m4.w, o[i]);
        }
    }

    float* op = out + (((size_t)(z * NQ + a) * NQ) + b) * CO;
    #pragma unroll
    for (int i = 0; i < CO; i += 4) {
        float4 v = make_float4(o[i], o[i + 1], o[i + 2], o[i + 3]);
        *reinterpret_cast<float4*>(op + i) = v;
    }
}

extern "C" void kernel_launch(void* const* d_in, const int* in_sizes, int n_in,
                              void* d_out, int out_size, void* d_ws, size_t ws_size,
                              hipStream_t stream) {
    const float* features = (const float*)d_in[0];
    const float* geometry = (const float*)d_in[1];
    const float* W1       = (const float*)d_in[2];
    const float* b1       = (const float*)d_in[3];
    const float* W2       = (const float*)d_in[4];
    const float* b2       = (const float*)d_in[5];
    float* out = (float*)d_out;

    // 2 blocks per (z,b): each covers 256 'a' values. 2*512*2 = 2048 blocks.
    fused_pairconv_kernel<<<2048, 256, 0, stream>>>(
        features, geometry, W1, b1, W2, b2, out);
}

// Round 2
// 50.191 us; speedup vs baseline: 1.5336x; 1.5336x over previous
//
#include <hip/hip_runtime.h>

// B=2, N=512, C_IN=16, C_OUT=16, HID=64
#define NQ   512
#define CI   16
#define CO   16
#define HIDN 64

typedef float sf16 __attribute__((ext_vector_type(16)));

// ---------------------------------------------------------------------------
// Kernel 1: M[zb][i][h] = sum_j f[zb][j] * W2[(i*16+j)*64 + h]   -> d_ws (4 MB)
// ---------------------------------------------------------------------------
__global__ __launch_bounds__(256) void compute_M_kernel(
    const float* __restrict__ features,   // [2*512,16]
    const float* __restrict__ W2,         // [256,64]
    float* __restrict__ Mws)              // [1024][1024]
{
    __shared__ float f_sm[CI];
    const int zb  = blockIdx.x;
    const int tid = threadIdx.x;
    if (tid < CI) f_sm[tid] = features[zb * CI + tid];
    __syncthreads();

    #pragma unroll
    for (int e = 0; e < 4; ++e) {
        int idx = tid + e * 256;        // 0..1023
        int i   = idx >> 6;             // C_OUT index
        int hh  = idx & 63;             // HID index
        float acc = 0.f;
        #pragma unroll
        for (int j = 0; j < CI; ++j)
            acc = fmaf(f_sm[j], W2[(i * CI + j) * HIDN + hh], acc);
        Mws[(size_t)zb * 1024 + idx] = acc;
    }
}

// ---------------------------------------------------------------------------
// Kernel 2: per (z,a,b): hv = gelu(W1·[rel,|rel|]+b1); out[i] = hv·M[zb][i][:] + c[i]
// M read through the SCALAR path (s_load_dwordx16 -> SGPRs).
// ---------------------------------------------------------------------------
__global__ __launch_bounds__(256) void apply_pairconv_kernel(
    const float* __restrict__ features,   // [2*512,16]
    const float* __restrict__ geometry,   // [2*512,3]
    const float* __restrict__ W1,         // [64,4]
    const float* __restrict__ b1,         // [64]
    const float* __restrict__ b2,         // [256]
    const float* __restrict__ Mws,        // [1024][1024]
    float* __restrict__ out)              // [2,512,512,16]
{
    __shared__ float W1_sm[HIDN * 4];
    __shared__ float b1_sm[HIDN];
    __shared__ float f_sm[CI];
    __shared__ float c_sm[CO];

    const int bid = blockIdx.x;
    const int zb  = bid >> 1;            // z*512 + b
    const int a0  = (bid & 1) << 8;
    const int z   = zb >> 9;
    const int b   = zb & 511;
    const int tid = threadIdx.x;

    W1_sm[tid] = W1[tid];
    if (tid < HIDN) b1_sm[tid] = b1[tid];
    if (tid < CI)   f_sm[tid]  = features[zb * CI + tid];
    __syncthreads();
    if (tid < CO) {
        float acc = 0.f;
        #pragma unroll
        for (int j = 0; j < CI; ++j)
            acc = fmaf(f_sm[j], b2[tid * CI + j], acc);
        c_sm[tid] = acc;
    }
    __syncthreads();

    const int a = a0 + tid;
    const float* ga = geometry + (size_t)(z * NQ + a) * 3;
    const float* gb = geometry + (size_t)(z * NQ + b) * 3;
    const float rx = gb[0] - ga[0];
    const float ry = gb[1] - ga[1];
    const float rz = gb[2] - ga[2];
    const float nrm = sqrtf(fmaf(rx, rx, fmaf(ry, ry, rz * rz)) + 1e-12f);

    // MLP1 + gelu (tanh approx, sigmoid form):
    // hv = x * 1/(1 + exp2(c * x * (1 + 0.044715 x^2))),  c = -2*sqrt(2/pi)*log2(e)
    float hv[HIDN];
    #pragma unroll
    for (int k = 0; k < HIDN; ++k) {
        float x = b1_sm[k];
        x = fmaf(rx,  W1_sm[k * 4 + 0], x);
        x = fmaf(ry,  W1_sm[k * 4 + 1], x);
        x = fmaf(rz,  W1_sm[k * 4 + 2], x);
        x = fmaf(nrm, W1_sm[k * 4 + 3], x);
        float x2 = x * x;
        float q  = fmaf(x2, 0.044715f, 1.0f);
        float e  = __builtin_amdgcn_exp2f((-2.3022082f * x) * q);  // exp(-2u)
        hv[k] = x * __builtin_amdgcn_rcpf(1.0f + e);               // x*sigmoid(2u)
    }

    // contraction: M slices pulled into SGPRs via scalar loads
    const float* Mzb = Mws + (size_t)zb * 1024;
    float o[CO];
    #pragma unroll 1
    for (int i = 0; i < CO; ++i) {
        const float* mi = Mzb + i * HIDN;
        sf16 m0, m1, m2, m3;
        asm volatile(
            "s_load_dwordx16 %0, %2, 0x0\n\t"
            "s_load_dwordx16 %1, %2, 0x40\n\t"
            "s_waitcnt lgkmcnt(0)"
            : "=s"(m0), "=s"(m1) : "s"(mi));
        float acc = c_sm[i];
        #pragma unroll
        for (int k = 0; k < 16; ++k) acc = fmaf(hv[k],      m0[k], acc);
        #pragma unroll
        for (int k = 0; k < 16; ++k) acc = fmaf(hv[16 + k], m1[k], acc);
        asm volatile(
            "s_load_dwordx16 %0, %2, 0x80\n\t"
            "s_load_dwordx16 %1, %2, 0xc0\n\t"
            "s_waitcnt lgkmcnt(0)"
            : "=s"(m2), "=s"(m3) : "s"(mi));
        #pragma unroll
        for (int k = 0; k < 16; ++k) acc = fmaf(hv[32 + k], m2[k], acc);
        #pragma unroll
        for (int k = 0; k < 16; ++k) acc = fmaf(hv[48 + k], m3[k], acc);
        o[i] = acc;
    }

    float* op = out + (((size_t)(z * NQ + a) * NQ) + b) * CO;
    #pragma unroll
    for (int i = 0; i < CO; i += 4)
        *reinterpret_cast<float4*>(op + i) = make_float4(o[i], o[i+1], o[i+2], o[i+3]);
}

// ---------------------------------------------------------------------------
// Fallback (round-1 proven kernel) if ws_size is too small for M.
// ---------------------------------------------------------------------------
__global__ __launch_bounds__(256) void fused_pairconv_kernel(
    const float* __restrict__ features, const float* __restrict__ geometry,
    const float* __restrict__ W1, const float* __restrict__ b1,
    const float* __restrict__ W2, const float* __restrict__ b2,
    float* __restrict__ out)
{
    __shared__ float M_sm[CO * HIDN];
    __shared__ float c_sm[CO];
    __shared__ float f_sm[CI];
    __shared__ float W1_sm[HIDN * 4];
    __shared__ float b1_sm[HIDN];

    const int bid = blockIdx.x;
    const int zb  = bid >> 1;
    const int a0  = (bid & 1) << 8;
    const int z   = zb >> 9;
    const int tid = threadIdx.x;

    W1_sm[tid] = W1[tid];
    if (tid < HIDN) b1_sm[tid] = b1[tid];
    if (tid < CI)   f_sm[tid]  = features[zb * CI + tid];
    __syncthreads();

    #pragma unroll
    for (int e = 0; e < 4; ++e) {
        int idx = tid + e * 256;
        int i = idx >> 6, hh = idx & 63;
        float acc = 0.f;
        #pragma unroll
        for (int j = 0; j < CI; ++j)
            acc = fmaf(f_sm[j], W2[(i * CI + j) * HIDN + hh], acc);
        M_sm[idx] = acc;
    }
    if (tid < CO) {
        float acc = 0.f;
        #pragma unroll
        for (int j = 0; j < CI; ++j)
            acc = fmaf(f_sm[j], b2[tid * CI + j], acc);
        c_sm[tid] = acc;
    }
    __syncthreads();

    const int a = a0 + tid;
    const float* ga = geometry + (size_t)(z * NQ + a) * 3;
    const float* gb = geometry + (size_t)(z * NQ + (zb & 511)) * 3;
    const float rx = gb[0] - ga[0];
    const float ry = gb[1] - ga[1];
    const float rz = gb[2] - ga[2];
    const float nrm = sqrtf(fmaf(rx, rx, fmaf(ry, ry, rz * rz)) + 1e-12f);

    float hv[HIDN];
    #pragma unroll
    for (int k = 0; k < HIDN; ++k) {
        float x = b1_sm[k];
        x = fmaf(rx,  W1_sm[k * 4 + 0], x);
        x = fmaf(ry,  W1_sm[k * 4 + 1], x);
        x = fmaf(rz,  W1_sm[k * 4 + 2], x);
        x = fmaf(nrm, W1_sm[k * 4 + 3], x);
        float x2 = x * x;
        float q  = fmaf(x2, 0.044715f, 1.0f);
        float e  = __builtin_amdgcn_exp2f((-2.3022082f * x) * q);
        hv[k] = x * __builtin_amdgcn_rcpf(1.0f + e);
    }

    float o[CO];
    #pragma unroll
    for (int i = 0; i < CO; ++i) o[i] = c_sm[i];
    #pragma unroll
    for (int i = 0; i < CO; ++i) {
        #pragma unroll
        for (int k = 0; k < HIDN; k += 4) {
            const float4 m4 = *reinterpret_cast<const float4*>(&M_sm[i * HIDN + k]);
            o[i] = fmaf(hv[k + 0], m4.x, o[i]);
            o[i] = fmaf(hv[k + 1], m4.y, o[i]);
            o[i] = fmaf(hv[k + 2], m4.z, o[i]);
            o[i] = fmaf(hv[k + 3], m4.w, o[i]);
        }
    }

    float* op = out + (((size_t)(z * NQ + a) * NQ) + (zb & 511)) * CO;
    #pragma unroll
    for (int i = 0; i < CO; i += 4)
        *reinterpret_cast<float4*>(op + i) = make_float4(o[i], o[i+1], o[i+2], o[i+3]);
}

extern "C" void kernel_launch(void* const* d_in, const int* in_sizes, int n_in,
                              void* d_out, int out_size, void* d_ws, size_t ws_size,
                              hipStream_t stream) {
    const float* features = (const float*)d_in[0];
    const float* geometry = (const float*)d_in[1];
    const float* W1       = (const float*)d_in[2];
    const float* b1       = (const float*)d_in[3];
    const float* W2       = (const float*)d_in[4];
    const float* b2       = (const float*)d_in[5];
    float* out = (float*)d_out;

    const size_t needM = (size_t)1024 * 1024 * sizeof(float);   // 4 MB
    if (ws_size >= needM) {
        float* Mws = (float*)d_ws;
        compute_M_kernel<<<1024, 256, 0, stream>>>(features, W2, Mws);
        apply_pairconv_kernel<<<2048, 256, 0, stream>>>(
            features, geometry, W1, b1, b2, Mws, out);
    } else {
        fused_pairconv_kernel<<<2048, 256, 0, stream>>>(
            features, geometry, W1, b1, W2, b2, out);
    }
}